// Round 3
// baseline (100.338 us; speedup 1.0000x reference)
//
#include <hip/hip_runtime.h>

#define BATCH   256
#define NCOL    576
#define MROW    144
#define ZLIFT   24
#define NIT     3
#define ROW_DEG 15
#define NEDGE   (MROW * ROW_DEG)                       // 2160
#define NSC     ((MROW/ZLIFT) * (NCOL/ZLIFT))          // 144 scale cells
#define NSCIT   (NSC * NIT)                            // 432

// Kernel 1: one wave per check row. Ballot+popcount compaction of the 15
// ones per row (ascending order preserved — argmin tie-break needs it).
// Packs column n (low 16 bits) with scale index sidx=(m/24)*24+n/24 (high).
__global__ __launch_bounds__(256) void build_cols_kernel(
    const int* __restrict__ H, int* __restrict__ pk)
{
    const int wave = (blockIdx.x * blockDim.x + threadIdx.x) >> 6;
    const int lane = threadIdx.x & 63;
    if (wave >= MROW) return;
    const int* row = H + (size_t)wave * NCOL;
    const int srow = (wave / ZLIFT) * (NCOL / ZLIFT);
    int base = 0;
    #pragma unroll
    for (int c0 = 0; c0 < NCOL; c0 += 64) {
        const int n = c0 + lane;
        const int present = (row[n] != 0) ? 1 : 0;
        const unsigned long long mask = __ballot(present);
        if (present) {
            const int rank = __popcll(mask & ((1ull << lane) - 1ull));
            const int idx = base + rank;
            if (idx < ROW_DEG)
                pk[wave * ROW_DEG + idx] = n | ((srow + n / ZLIFT) << 16);
        }
        base += __popcll(mask);
    }
}

// Kernel 2: ONE WAVE per frame (64-thread block). All state in LDS.
// M is never materialized: M[e] = r[n] + colsum_prev[n] - E_prev[e].
// E is row-owned (lane-private across iterations); colsum ping-pongs.
__global__ __launch_bounds__(64) void ldpc_decode_kernel(
    const float* __restrict__ r,
    const float* __restrict__ alpha,
    const float* __restrict__ beta,
    const int*   __restrict__ pk,
    float*       __restrict__ out)
{
    __shared__ float r_s[NCOL];
    __shared__ float cs[2][NCOL];      // ping-pong column sums
    __shared__ float E_s[NEDGE];
    __shared__ float a_s[NSCIT];
    __shared__ float b_s[NSCIT];
    __shared__ int   c_s[NEDGE];       // packed n | sidx<<16

    const int b    = blockIdx.x;
    const int lane = threadIdx.x;

    for (int n = lane; n < NCOL; n += 64) {
        r_s[n] = r[(size_t)b * NCOL + n];
        cs[0][n] = 0.0f;
    }
    for (int e = lane; e < NEDGE; e += 64) {
        c_s[e] = pk[e];
        E_s[e] = 0.0f;
    }
    for (int i = lane; i < NSCIT; i += 64) {
        a_s[i] = alpha[i];
        b_s[i] = beta[i];
    }
    __syncthreads();

    for (int it = 0; it < NIT; ++it) {
        float* prev = cs[it & 1];
        float* next = cs[(it + 1) & 1];
        for (int n = lane; n < NCOL; n += 64) next[n] = 0.0f;
        __syncthreads();

        for (int m = lane; m < MROW; m += 64) {
            int   pks[ROW_DEG];
            float vals[ROW_DEG];
            float min1 = INFINITY, min2 = INFINITY;
            int   kmin = -1;
            float sprod = 1.0f;
            // Pass 1: recompute M on the fly, min-2 magnitudes
            // (strict < == top_k first-occurrence tie-break), sign product.
            #pragma unroll
            for (int k = 0; k < ROW_DEG; ++k) {
                const int e = m * ROW_DEG + k;
                const int p = c_s[e];
                pks[k] = p;
                const int n = p & 0xFFFF;
                const float v = r_s[n] + prev[n] - E_s[e];
                vals[k] = v;
                const float av = fabsf(v);
                const float s = (v > 0.0f) ? 1.0f : ((v < 0.0f) ? -1.0f : 0.0f);
                sprod *= s;
                if (av < min1)      { min2 = min1; min1 = av; kmin = k; }
                else if (av < min2) { min2 = av; }
            }
            // Pass 2: extrinsic messages + column-sum accumulation.
            #pragma unroll
            for (int k = 0; k < ROW_DEG; ++k) {
                const int e = m * ROW_DEG + k;
                const int p = pks[k];
                const int n = p & 0xFFFF;
                const int sidx = p >> 16;
                const float v = vals[k];
                const float s = (v > 0.0f) ? 1.0f : ((v < 0.0f) ? -1.0f : 0.0f);
                const float a  = a_s[sidx * NIT + it];
                const float bt = b_s[sidx * NIT + it];
                const float eabs = (k == kmin) ? min2 : min1;
                float mag = eabs - bt;
                if (mag < 0.0f) mag = 0.0f;
                const float E = a * (sprod * s) * mag;
                E_s[e] = E;
                atomicAdd(&next[n], E);
            }
        }
        __syncthreads();
    }

    const float* fin = cs[NIT & 1];
    for (int n = lane; n < NCOL; n += 64)
        out[(size_t)b * NCOL + n] = r_s[n] + fin[n];
}

extern "C" void kernel_launch(void* const* d_in, const int* in_sizes, int n_in,
                              void* d_out, int out_size, void* d_ws, size_t ws_size,
                              hipStream_t stream) {
    const float* r     = (const float*)d_in[0];
    const float* alpha = (const float*)d_in[1];
    const float* beta  = (const float*)d_in[2];
    const int*   H     = (const int*)d_in[3];
    float* out = (float*)d_out;
    int*   pk  = (int*)d_ws;   // NEDGE packed ints

    build_cols_kernel<<<(MROW * 64 + 255) / 256, 256, 0, stream>>>(H, pk);
    ldpc_decode_kernel<<<BATCH, 64, 0, stream>>>(r, alpha, beta, pk, out);
}

// Round 4
// 79.867 us; speedup vs baseline: 1.2563x; 1.2563x over previous
//
#include <hip/hip_runtime.h>

#define BATCH   256
#define NCOL    576
#define MROW    144
#define ZLIFT   24
#define NIT     3
#define ROW_DEG 15
#define NEDGE   (MROW * ROW_DEG)                 // 2160
#define NSCIT   ((MROW/ZLIFT) * (NCOL/ZLIFT) * NIT)  // 432
#define CCAP    17   // per-column edge capacity; 17 is coprime with 32 banks

// Kernel 1: one wave per check row. Ballot+popcount compaction of the 15
// ones per row (ascending order preserved — argmin tie-break needs it).
// Packs column n (low 16 bits) with scale index sidx=(m/24)*24+n/24 (high).
__global__ __launch_bounds__(256) void build_cols_kernel(
    const int* __restrict__ H, int* __restrict__ pk)
{
    const int wave = (blockIdx.x * blockDim.x + threadIdx.x) >> 6;
    const int lane = threadIdx.x & 63;
    if (wave >= MROW) return;
    const int* row = H + (size_t)wave * NCOL;
    const int srow = (wave / ZLIFT) * (NCOL / ZLIFT);
    int base = 0;
    #pragma unroll
    for (int c0 = 0; c0 < NCOL; c0 += 64) {
        const int n = c0 + lane;
        const int present = (row[n] != 0) ? 1 : 0;
        const unsigned long long mask = __ballot(present);
        if (present) {
            const int rank = __popcll(mask & ((1ull << lane) - 1ull));
            const int idx = base + rank;
            if (idx < ROW_DEG)
                pk[wave * ROW_DEG + idx] = n | ((srow + n / ZLIFT) << 16);
        }
        base += __popcll(mask);
    }
}

// Kernel 2: one block (256 threads, 4 waves) per frame.
// Thread tid<144 owns check row tid: its column indices, channel LLRs, and
// previous-iteration E messages stay in REGISTERS across iterations.
// Column sums are computed by a CSC gather phase (no per-iteration atomics).
__global__ __launch_bounds__(256) void ldpc_decode_kernel(
    const float* __restrict__ r,
    const float* __restrict__ alpha,
    const float* __restrict__ beta,
    const int*   __restrict__ pk,
    float*       __restrict__ out)
{
    __shared__ float r_s[NCOL];
    __shared__ float cs[2][NCOL];        // ping-pong column sums
    __shared__ float E_s[NEDGE];
    __shared__ float a_s[NSCIT];
    __shared__ float b_s[NSCIT];
    __shared__ int   c_s[NEDGE];         // packed n | sidx<<16
    __shared__ int   ccnt[NCOL];         // per-column degree
    __shared__ int   cedge[NCOL * CCAP]; // per-column edge ids (padded 17)

    const int b   = blockIdx.x;
    const int tid = threadIdx.x;

    // Stage inputs, zero counters.
    for (int n = tid; n < NCOL; n += 256) {
        r_s[n]   = r[(size_t)b * NCOL + n];
        cs[0][n] = 0.0f;
        ccnt[n]  = 0;
    }
    for (int e = tid; e < NEDGE; e += 256) c_s[e] = pk[e];
    for (int i = tid; i < NSCIT; i += 256) { a_s[i] = alpha[i]; b_s[i] = beta[i]; }
    __syncthreads();

    // One-time CSC build (LDS atomics; order within a column is irrelevant
    // up to fp-sum rounding, far below threshold).
    for (int e = tid; e < NEDGE; e += 256) {
        const int n = c_s[e] & 0xFFFF;
        const int slot = atomicAdd(&ccnt[n], 1);
        if (slot < CCAP) cedge[n * CCAP + slot] = e;
    }

    // Row-owned register state.
    int   pk_r[ROW_DEG];
    float r_r[ROW_DEG];
    float E_r[ROW_DEG];
    const bool is_row = (tid < MROW);
    if (is_row) {
        #pragma unroll
        for (int k = 0; k < ROW_DEG; ++k) {
            const int p = c_s[tid * ROW_DEG + k];
            pk_r[k] = p;
            r_r[k]  = r_s[p & 0xFFFF];
            E_r[k]  = 0.0f;
        }
    }
    __syncthreads();

    for (int it = 0; it < NIT; ++it) {
        float* prev = cs[it & 1];
        float* next = cs[(it + 1) & 1];

        // Check-node phase: M recomputed on the fly (r + prevsum - E_prev),
        // min-2 with strict < (== top_k first-occurrence tie-break), sign prod.
        if (is_row) {
            float vals[ROW_DEG];
            float min1 = INFINITY, min2 = INFINITY;
            int   kmin = -1;
            float sprod = 1.0f;
            #pragma unroll
            for (int k = 0; k < ROW_DEG; ++k) {
                const int n = pk_r[k] & 0xFFFF;
                const float v = r_r[k] + prev[n] - E_r[k];
                vals[k] = v;
                const float av = fabsf(v);
                const float s = (v > 0.0f) ? 1.0f : ((v < 0.0f) ? -1.0f : 0.0f);
                sprod *= s;
                if (av < min1)      { min2 = min1; min1 = av; kmin = k; }
                else if (av < min2) { min2 = av; }
            }
            #pragma unroll
            for (int k = 0; k < ROW_DEG; ++k) {
                const int sidx = pk_r[k] >> 16;
                const float v = vals[k];
                const float s = (v > 0.0f) ? 1.0f : ((v < 0.0f) ? -1.0f : 0.0f);
                const float a  = a_s[sidx * NIT + it];
                const float bt = b_s[sidx * NIT + it];
                const float eabs = (k == kmin) ? min2 : min1;
                float mag = eabs - bt;
                if (mag < 0.0f) mag = 0.0f;
                const float E = a * (sprod * s) * mag;
                E_r[k] = E;
                E_s[tid * ROW_DEG + k] = E;
            }
        }
        __syncthreads();   // E_s complete

        // Variable-node phase: gather column sums via CSC (overwrite, no zeroing).
        for (int n = tid; n < NCOL; n += 256) {
            int deg = ccnt[n];
            if (deg > CCAP) deg = CCAP;
            float sum = 0.0f;
            for (int i = 0; i < deg; ++i) sum += E_s[cedge[n * CCAP + i]];
            next[n] = sum;
        }
        __syncthreads();   // next complete before reuse as prev
    }

    const float* fin = cs[NIT & 1];
    for (int n = tid; n < NCOL; n += 256)
        out[(size_t)b * NCOL + n] = r_s[n] + fin[n];
}

extern "C" void kernel_launch(void* const* d_in, const int* in_sizes, int n_in,
                              void* d_out, int out_size, void* d_ws, size_t ws_size,
                              hipStream_t stream) {
    const float* r     = (const float*)d_in[0];
    const float* alpha = (const float*)d_in[1];
    const float* beta  = (const float*)d_in[2];
    const int*   H     = (const int*)d_in[3];
    float* out = (float*)d_out;
    int*   pk  = (int*)d_ws;   // NEDGE packed ints

    build_cols_kernel<<<(MROW * 64 + 255) / 256, 256, 0, stream>>>(H, pk);
    ldpc_decode_kernel<<<BATCH, 256, 0, stream>>>(r, alpha, beta, pk, out);
}

// Round 5
// 72.783 us; speedup vs baseline: 1.3786x; 1.0973x over previous
//
#include <hip/hip_runtime.h>

#define BATCH   256
#define NCOL    576
#define MROW    144
#define ZLIFT   24
#define NIT     3
#define ROW_DEG 15
#define NEDGE   (MROW * ROW_DEG)                 // 2160
#define NSCIT   ((MROW/ZLIFT) * (NCOL/ZLIFT) * NIT)  // 432
#define TPB     512                              // 8 waves/CU (1 block/CU)

// Kernel 1: one wave per check row. Ballot+popcount compaction of the 15
// ones per row (ascending order preserved — argmin tie-break needs it).
// Packs column n (low 16 bits) with scale index sidx=(m/24)*24+n/24 (high).
__global__ __launch_bounds__(256) void build_cols_kernel(
    const int* __restrict__ H, int* __restrict__ pk)
{
    const int wave = (blockIdx.x * blockDim.x + threadIdx.x) >> 6;
    const int lane = threadIdx.x & 63;
    if (wave >= MROW) return;
    const int* row = H + (size_t)wave * NCOL;
    const int srow = (wave / ZLIFT) * (NCOL / ZLIFT);
    int base = 0;
    #pragma unroll
    for (int c0 = 0; c0 < NCOL; c0 += 64) {
        const int n = c0 + lane;
        const int present = (row[n] != 0) ? 1 : 0;
        const unsigned long long mask = __ballot(present);
        if (present) {
            const int rank = __popcll(mask & ((1ull << lane) - 1ull));
            const int idx = base + rank;
            if (idx < ROW_DEG)
                pk[wave * ROW_DEG + idx] = n | ((srow + n / ZLIFT) << 16);
        }
        base += __popcll(mask);
    }
}

// Kernel 2: one block (512 threads, 8 waves) per frame.
// Thread tid<144 owns check row tid; its column indices, channel LLRs,
// previous E messages, and CSC slots all live in REGISTERS.
// E_s is stored in CSC (column-major) order so the variable-node phase
// reads contiguous runs — no indirection table, no per-iteration atomics.
__global__ __launch_bounds__(TPB) void ldpc_decode_kernel(
    const float* __restrict__ r,
    const float* __restrict__ alpha,
    const float* __restrict__ beta,
    const int*   __restrict__ pk,
    float*       __restrict__ out)
{
    __shared__ float r_s[NCOL];
    __shared__ float cs[2][NCOL];      // ping-pong column sums
    __shared__ float E_s[NEDGE];       // CSC-ordered extrinsic messages
    __shared__ float a_s[NSCIT];
    __shared__ float b_s[NSCIT];
    __shared__ int   cdeg[NCOL];       // per-column degree (atomic, then final)
    __shared__ int   cstart[NCOL];     // exclusive prefix of cdeg

    const int b   = blockIdx.x;
    const int tid = threadIdx.x;

    // ---- setup ----
    for (int n = tid; n < NCOL; n += TPB) {
        r_s[n]   = r[(size_t)b * NCOL + n];
        cs[0][n] = 0.0f;
        cdeg[n]  = 0;
    }
    if (tid < NSCIT) { a_s[tid] = alpha[tid]; b_s[tid] = beta[tid]; }
    __syncthreads();

    const bool is_row = (tid < MROW);
    int   pk_r[ROW_DEG];    // packed n | sidx<<16
    float r_r[ROW_DEG];     // channel LLR at each edge's column
    float E_r[ROW_DEG];     // previous-iteration extrinsic message
    int   slot_r[ROW_DEG];  // CSC slot (rank j first, then cstart[n]+j)
    if (is_row) {
        #pragma unroll
        for (int k = 0; k < ROW_DEG; ++k) {
            const int p = pk[tid * ROW_DEG + k];
            pk_r[k] = p;
            const int n = p & 0xFFFF;
            r_r[k]  = r_s[n];
            E_r[k]  = 0.0f;
            slot_r[k] = atomicAdd(&cdeg[n], 1);   // rank within column
        }
    }
    __syncthreads();

    // Wave 0: exclusive prefix scan cdeg -> cstart (9 cols/lane, shuffle scan).
    if (tid < 64) {
        int local[9];
        int run = 0;
        #pragma unroll
        for (int j = 0; j < 9; ++j) { local[j] = cdeg[tid * 9 + j]; run += local[j]; }
        int scan = run;
        #pragma unroll
        for (int off = 1; off < 64; off <<= 1) {
            int up = __shfl_up(scan, off);
            if (tid >= off) scan += up;
        }
        int acc = scan - run;   // exclusive
        #pragma unroll
        for (int j = 0; j < 9; ++j) { cstart[tid * 9 + j] = acc; acc += local[j]; }
    }
    __syncthreads();

    if (is_row) {
        #pragma unroll
        for (int k = 0; k < ROW_DEG; ++k)
            slot_r[k] += cstart[pk_r[k] & 0xFFFF];
    }
    // (no barrier needed: slot_r is register-private, E_s not yet read)

    // ---- iterations ----
    for (int it = 0; it < NIT; ++it) {
        float* prev = cs[it & 1];
        float* next = cs[(it + 1) & 1];

        // Check-node phase: M = r + prevsum - E_prev recomputed on the fly;
        // min-2 with strict < (== top_k first-occurrence tie-break); sign prod.
        if (is_row) {
            float vals[ROW_DEG];
            float min1 = INFINITY, min2 = INFINITY;
            int   kmin = -1;
            float sprod = 1.0f;
            #pragma unroll
            for (int k = 0; k < ROW_DEG; ++k) {
                const int n = pk_r[k] & 0xFFFF;
                const float v = r_r[k] + prev[n] - E_r[k];
                vals[k] = v;
                const float av = fabsf(v);
                const float s = (v > 0.0f) ? 1.0f : ((v < 0.0f) ? -1.0f : 0.0f);
                sprod *= s;
                if (av < min1)      { min2 = min1; min1 = av; kmin = k; }
                else if (av < min2) { min2 = av; }
            }
            #pragma unroll
            for (int k = 0; k < ROW_DEG; ++k) {
                const int sidx = pk_r[k] >> 16;
                const float v = vals[k];
                const float s = (v > 0.0f) ? 1.0f : ((v < 0.0f) ? -1.0f : 0.0f);
                const float a  = a_s[sidx * NIT + it];
                const float bt = b_s[sidx * NIT + it];
                const float eabs = (k == kmin) ? min2 : min1;
                float mag = eabs - bt;
                if (mag < 0.0f) mag = 0.0f;
                const float E = a * (sprod * s) * mag;
                E_r[k] = E;
                E_s[slot_r[k]] = E;
            }
        }
        __syncthreads();   // E_s complete

        // Variable-node phase: contiguous CSC gather (overwrite, no zeroing).
        for (int n = tid; n < NCOL; n += TPB) {
            const int s0  = cstart[n];
            const int deg = cdeg[n];
            float sum = 0.0f;
            for (int i = 0; i < deg; ++i) sum += E_s[s0 + i];
            next[n] = sum;
        }
        __syncthreads();   // next complete before reuse as prev
    }

    const float* fin = cs[NIT & 1];
    for (int n = tid; n < NCOL; n += TPB)
        out[(size_t)b * NCOL + n] = r_s[n] + fin[n];
}

extern "C" void kernel_launch(void* const* d_in, const int* in_sizes, int n_in,
                              void* d_out, int out_size, void* d_ws, size_t ws_size,
                              hipStream_t stream) {
    const float* r     = (const float*)d_in[0];
    const float* alpha = (const float*)d_in[1];
    const float* beta  = (const float*)d_in[2];
    const int*   H     = (const int*)d_in[3];
    float* out = (float*)d_out;
    int*   pk  = (int*)d_ws;   // NEDGE packed ints

    build_cols_kernel<<<(MROW * 64 + 255) / 256, 256, 0, stream>>>(H, pk);
    ldpc_decode_kernel<<<BATCH, TPB, 0, stream>>>(r, alpha, beta, pk, out);
}